// Round 3
// baseline (634.029 us; speedup 1.0000x reference)
//
#include <hip/hip_runtime.h>
#include <math.h>

// ---------------------------------------------------------------------------
// APQBAttention on MI355X (gfx950), round 3.
//   r2 counters: attn latency-bound (Mfma 4%, VALU 20%, HBM 16%); GEMMs
//   8-way LDS bank-conflicted (stride 32 f16) + grid 256 = 1 block/CU.
//   Changes:
//     - k_mask: noise (256MB) -> 1-bit keep mask (8MB), streaming float4
//     - k_attn: consumes mask words (4 x u64 / tile), K reg-prefetch,
//       scale folded into Q
//     - k_gemm: LDS stride 40 (conflict-free frag reads), 128x64 tile
//       (grid 512), global prefetch under MFMAs, V-transpose via LDS epilogue
// ---------------------------------------------------------------------------

typedef _Float16 f16;
typedef _Float16 f16x8 __attribute__((ext_vector_type(8)));
typedef float    f32x4 __attribute__((ext_vector_type(4)));
typedef unsigned long long u64;

constexpr int EMB = 1024;
constexpr int NH  = 16;
constexpr int HD  = 64;
constexpr int NB  = 4;
constexpr int SEQ = 1024;
constexpr int MT  = NB * SEQ;   // 4096 rows

// workspace layout (bytes); total = 48 MB + 256 B
constexpr size_t WS_SC  = 0;                         // scalars (64B used)
constexpr size_t WS_XH  = 256;                       // x f16; mask reuses this after QKV GEMMs
constexpr size_t SZ_XH  = (size_t)MT * EMB * 2;      // 8 MB
constexpr size_t SZ_W   = (size_t)EMB * EMB * 2;     // 2 MB
constexpr size_t WS_WQH = WS_XH + SZ_XH;             // 4 weights contiguous
constexpr size_t SZ_QH  = (size_t)NB * NH * SEQ * HD * 2;  // 8 MB
constexpr size_t WS_QH  = WS_WQH + 4 * SZ_W;
constexpr size_t WS_KH  = WS_QH + SZ_QH;
constexpr size_t WS_VTH = WS_KH + SZ_QH;             // V stored [B,H,D,T]
constexpr size_t WS_OA  = WS_VTH + SZ_QH;            // attn out [B,T,E] f16

#define MFMA16(a,b,c) __builtin_amdgcn_mfma_f32_16x16x32_f16((a),(b),(c),0,0,0)

// ---- scalar setup: T_mean (fp64) and 1/cdrop ------------------------------
__global__ void k_setup(const float* __restrict__ theta, float* __restrict__ sc) {
  if (threadIdx.x == 0 && blockIdx.x == 0) {
    double acc = 0.0;
    for (int h = 0; h < NH; ++h) {
      double th = (double)theta[h];
      th = 1.0 / (1.0 + exp(-th)) * (M_PI * 0.5);   // sigmoid * pi/2
      acc += fabs(sin(2.0 * th));
    }
    double tm = acc / (double)NH;
    sc[0] = (float)tm;
    sc[1] = (float)(1.0 / (1.0 - tm + 1e-8));       // inv cdrop
    ((double*)(sc + 2))[0] = tm;                    // fp64 copy for mask compare
  }
}

// ---- f32 -> f16 convert, 8 elems/thread -----------------------------------
__global__ void k_cvt8(const float* __restrict__ src, f16* __restrict__ dst, int n8) {
  int i = blockIdx.x * blockDim.x + threadIdx.x;
  if (i >= n8) return;
  const float4* s = (const float4*)src + 2 * (size_t)i;
  float4 a = s[0], b = s[1];
  f16x8 o;
  o[0] = (f16)a.x; o[1] = (f16)a.y; o[2] = (f16)a.z; o[3] = (f16)a.w;
  o[4] = (f16)b.x; o[5] = (f16)b.y; o[6] = (f16)b.z; o[7] = (f16)b.w;
  *(f16x8*)(dst + 8 * (size_t)i) = o;
}

// ---- 4 weight matrices -> contiguous f16 ----------------------------------
__global__ void k_cvtW(const float* __restrict__ s0, const float* __restrict__ s1,
                       const float* __restrict__ s2, const float* __restrict__ s3,
                       f16* __restrict__ dst) {
  int i = blockIdx.x * blockDim.x + threadIdx.x;   // 0 .. 4*131072-1
  int w   = i >> 17;
  int off = i & 131071;
  const float* src = (w == 0) ? s0 : (w == 1) ? s1 : (w == 2) ? s2 : s3;
  const float4* s = (const float4*)src + 2 * (size_t)off;
  float4 a = s[0], b = s[1];
  f16x8 o;
  o[0] = (f16)a.x; o[1] = (f16)a.y; o[2] = (f16)a.z; o[3] = (f16)a.w;
  o[4] = (f16)b.x; o[5] = (f16)b.y; o[6] = (f16)b.z; o[7] = (f16)b.w;
  *(f16x8*)(dst + ((size_t)w << 20) + 8 * (size_t)off) = o;
}

// ---- noise -> 1-bit keep mask (bit s&63 of word [bh][t][s>>6]) ------------
// each thread builds one u64 from its own 64 consecutive floats (16 float4s;
// lanes' loads interleave across 64B lines, L1 catches the 4x reuse)
__global__ __launch_bounds__(256) void k_mask(const float* __restrict__ noise,
                                              const float* __restrict__ sc,
                                              u64* __restrict__ mask) {
  const double tmean = *(const double*)(sc + 2);
  const int NW = NB * NH * SEQ * (SEQ / 64);   // 1048576 words
  int stride = gridDim.x * blockDim.x;
  for (int w = blockIdx.x * blockDim.x + threadIdx.x; w < NW; w += stride) {
    const float4* p = (const float4*)(noise + (size_t)w * 64);
    u64 m = 0;
    #pragma unroll
    for (int j = 0; j < 16; ++j) {
      float4 v = p[j];
      u64 nib = (u64)(((double)v.x > tmean) ? 1 : 0)
              | ((u64)(((double)v.y > tmean) ? 1 : 0) << 1)
              | ((u64)(((double)v.z > tmean) ? 1 : 0) << 2)
              | ((u64)(((double)v.w > tmean) ? 1 : 0) << 3);
      m |= nib << (4 * j);
    }
    mask[w] = m;
  }
}

// ---- GEMM: C[M,N] = A[M,K] * W[N,K]^T + bias, then *oscale ----------------
// 128x64 tile (M x N), BK=32, 4 waves (2x2), wave = 64x32 (4x2 MFMAs).
// LDS stride 40 f16: frag-read bank starts 20c mod 32 tile all 32 banks.
// OUTMODE 0: f16 out [B,H,T,D] (Q with oscale=0.125, K)
// OUTMODE 1: f16 out [B,H,D,T] via LDS transpose (V)
// OUTMODE 2: f32 out [M,N] (final projection)
template <int OUTMODE>
__global__ __launch_bounds__(256) void k_gemm(
    const f16* __restrict__ A, const f16* __restrict__ Bw,
    const float* __restrict__ bias, float oscale, void* __restrict__ outp)
{
  __shared__ f16 As[128 * 40];
  __shared__ f16 Bs[64 * 40];
  const int tid  = threadIdx.x;
  const int wave = tid >> 6, lane = tid & 63;
  const int c = lane & 15, g = lane >> 4;
  const int wr = wave >> 1, wc = wave & 1;     // wave row/col in 2x2
  const int bn0 = blockIdx.x * 64;
  const int bm0 = blockIdx.y * 128;

  const int srow = tid >> 2;        // 0..63
  const int scol = (tid & 3) * 8;   // f16 offset within BK=32

  f32x4 acc[4][2];
  #pragma unroll
  for (int i = 0; i < 4; ++i)
    #pragma unroll
    for (int j = 0; j < 2; ++j) acc[i][j] = (f32x4){0.f, 0.f, 0.f, 0.f};

  const f16* Ap = A  + (size_t)bm0 * EMB;
  const f16* Bp = Bw + (size_t)bn0 * EMB;

  // prefetch k0 = 0
  int4 ra0 = *(const int4*)(Ap + (size_t)srow        * EMB + scol);
  int4 ra1 = *(const int4*)(Ap + (size_t)(srow + 64) * EMB + scol);
  int4 rb0 = *(const int4*)(Bp + (size_t)srow        * EMB + scol);

  for (int k0 = 0; k0 < EMB; k0 += 32) {
    __syncthreads();   // previous iteration's frag reads complete
    *(int4*)(As + srow * 40 + scol)        = ra0;
    *(int4*)(As + (srow + 64) * 40 + scol) = ra1;
    *(int4*)(Bs + srow * 40 + scol)        = rb0;
    __syncthreads();

    // prefetch next k-step under the MFMAs (clamped; last iter redundant)
    int k1 = (k0 + 32 < EMB) ? k0 + 32 : k0;
    ra0 = *(const int4*)(Ap + (size_t)srow        * EMB + k1 + scol);
    ra1 = *(const int4*)(Ap + (size_t)(srow + 64) * EMB + k1 + scol);
    rb0 = *(const int4*)(Bp + (size_t)srow        * EMB + k1 + scol);

    f16x8 af[4], bf[2];
    #pragma unroll
    for (int mi = 0; mi < 4; ++mi)
      af[mi] = *(const f16x8*)(As + (wr * 64 + mi * 16 + c) * 40 + g * 8);
    #pragma unroll
    for (int nj = 0; nj < 2; ++nj)
      bf[nj] = *(const f16x8*)(Bs + (wc * 32 + nj * 16 + c) * 40 + g * 8);
    #pragma unroll
    for (int mi = 0; mi < 4; ++mi)
      #pragma unroll
      for (int nj = 0; nj < 2; ++nj)
        acc[mi][nj] = MFMA16(af[mi], bf[nj], acc[mi][nj]);
  }

  if (OUTMODE == 1) {
    // transpose 64x32 wave tile via LDS, store [B,H,D,T] as 16B rows
    __syncthreads();                       // everyone done with As/Bs
    f16* T = As + wave * (16 * 36);        // 576 f16 per wave (fits in As)
    f16* outh = (f16*)outp;
    const int f0 = bn0 + wc * 32;          // multiple of 32, within one head
    const int h  = f0 >> 6;
    const int dl = lane & 31;              // local d
    const int th = lane >> 5;              // t half (0/1)
    #pragma unroll
    for (int mi = 0; mi < 4; ++mi) {
      #pragma unroll
      for (int nj = 0; nj < 2; ++nj)
        #pragma unroll
        for (int i = 0; i < 4; ++i) {
          int col = f0 + nj * 16 + c;
          T[(g * 4 + i) * 36 + nj * 16 + c] = (f16)(acc[mi][nj][i] + bias[col]);
        }
      // wave-private LDS: compiler orders write->read via lgkmcnt
      int row0 = bm0 + wr * 64 + mi * 16;
      int b = row0 >> 10, t0 = (row0 & 1023) + th * 8;
      f16x8 o;
      #pragma unroll
      for (int t = 0; t < 8; ++t) o[t] = T[(th * 8 + t) * 36 + dl];
      int d = (f0 & 63) + dl - (wc * 32);  // = dl + wc*32 - wc*32 ... d local in head:
      d = (wc * 32 + dl) & 63;             // f0%64 == wc*32
      size_t idx = (((size_t)(b * NH + h)) * HD + d) * SEQ + t0;
      *(f16x8*)(outh + idx) = o;
    }
    return;
  }

  // OUTMODE 0 / 2 epilogue: D layout row=(lane>>4)*4+i, col=lane&15
  #pragma unroll
  for (int mi = 0; mi < 4; ++mi) {
    #pragma unroll
    for (int nj = 0; nj < 2; ++nj) {
      #pragma unroll
      for (int i = 0; i < 4; ++i) {
        int row = bm0 + wr * 64 + mi * 16 + g * 4 + i;   // b*SEQ + t
        int col = bn0 + wc * 32 + nj * 16 + c;           // feature f
        float v = (acc[mi][nj][i] + bias[col]) * oscale;
        if (OUTMODE == 2) {
          ((float*)outp)[(size_t)row * EMB + col] = v;
        } else {
          int b = row >> 10, t = row & 1023;
          int h = col >> 6,  d = col & 63;
          ((f16*)outp)[(((size_t)(b * NH + h)) * SEQ + t) * HD + d] = (f16)v;
        }
      }
    }
  }
}

// ---- flash attention: one wave per 16 Q rows, KV tiles of 64 --------------
// Q pre-scaled by 1/8 in its GEMM. K register-prefetched one tile ahead.
// Dropout via bitmask words (4 x u64 per tile, L1/L2 broadcast loads).
__global__ __launch_bounds__(256) void k_attn(
    const f16* __restrict__ Q, const f16* __restrict__ K, const f16* __restrict__ Vt,
    const u64* __restrict__ Mask, const float* __restrict__ sc,
    f16* __restrict__ Oa)
{
  __shared__ f16 Pl[4][16 * 72];   // per-wave P tile, stride 72
  const int tid  = threadIdx.x;
  const int wave = tid >> 6, lane = tid & 63;
  const int c = lane & 15, g = lane >> 4;
  const int bh = blockIdx.y;                 // b*NH + h
  const int b  = bh >> 4, h = bh & 15;
  const int q0 = blockIdx.x * 64 + wave * 16;

  const float inv_cdrop = sc[1];

  const f16* Qp  = Q  + ((size_t)bh * SEQ + q0) * HD;
  const f16* Kp  = K  + (size_t)bh * SEQ * HD;
  const f16* Vp  = Vt + (size_t)bh * HD * SEQ;
  const u64* Mp  = Mask + (size_t)bh * SEQ * 16;

  // Q A-frags (loop invariant): A[row=c][k = kc*32 + g*8 + j]
  f16x8 qa[2];
  qa[0] = *(const f16x8*)(Qp + c * HD + g * 8);
  qa[1] = *(const f16x8*)(Qp + c * HD + 32 + g * 8);

  f32x4 oacc[4];
  #pragma unroll
  for (int n = 0; n < 4; ++n) oacc[n] = (f32x4){0.f, 0.f, 0.f, 0.f};
  float mrun[4], lrun[4];
  #pragma unroll
  for (int i = 0; i < 4; ++i) { mrun[i] = -1e30f; lrun[i] = 0.f; }

  f16* myP = &Pl[wave][0];

  // preload K tile 0
  f16x8 kb[8];
  #pragma unroll
  for (int kc = 0; kc < 2; ++kc)
    #pragma unroll
    for (int n = 0; n < 4; ++n)
      kb[kc * 4 + n] = *(const f16x8*)(Kp + (size_t)(n * 16 + c) * HD + kc * 32 + g * 8);

  for (int ts = 0; ts < 16; ++ts) {
    // mask words early (independent loads)
    u64 mw[4];
    #pragma unroll
    for (int i = 0; i < 4; ++i)
      mw[i] = Mp[(size_t)(q0 + g * 4 + i) * 16 + ts];

    // ---- S = Q K^T (16 x 64), Q pre-scaled ----
    f32x4 sa[4];
    #pragma unroll
    for (int n = 0; n < 4; ++n) sa[n] = (f32x4){0.f, 0.f, 0.f, 0.f};
    #pragma unroll
    for (int kc = 0; kc < 2; ++kc)
      #pragma unroll
      for (int n = 0; n < 4; ++n)
        sa[n] = MFMA16(qa[kc], kb[kc * 4 + n], sa[n]);

    // ---- prefetch K for next tile (hidden under softmax + PV) ----
    {
      int tsn = (ts < 15) ? ts + 1 : 15;
      const f16* Kn = Kp + (size_t)tsn * 64 * HD;
      #pragma unroll
      for (int kc = 0; kc < 2; ++kc)
        #pragma unroll
        for (int n = 0; n < 4; ++n)
          kb[kc * 4 + n] = *(const f16x8*)(Kn + (size_t)(n * 16 + c) * HD + kc * 32 + g * 8);
    }

    // ---- online softmax (rows live at (g,i) across 16 lanes of c) ----
    float rmx[4];
    #pragma unroll
    for (int i = 0; i < 4; ++i)
      rmx[i] = fmaxf(fmaxf(sa[0][i], sa[1][i]), fmaxf(sa[2][i], sa[3][i]));
    #pragma unroll
    for (int off = 1; off < 16; off <<= 1)
      #pragma unroll
      for (int i = 0; i < 4; ++i)
        rmx[i] = fmaxf(rmx[i], __shfl_xor(rmx[i], off, 64));

    float al[4], rs[4];
    #pragma unroll
    for (int i = 0; i < 4; ++i) {
      float mn = fmaxf(mrun[i], rmx[i]);
      al[i] = __expf(mrun[i] - mn);
      mrun[i] = mn;
      rs[i] = 0.f;
    }
    #pragma unroll
    for (int n = 0; n < 4; ++n)
      #pragma unroll
      for (int i = 0; i < 4; ++i) {
        float p = __expf(sa[n][i] - mrun[i]);
        sa[n][i] = p;                 // unmasked p
        rs[i] += p;
      }
    #pragma unroll
    for (int off = 1; off < 16; off <<= 1)
      #pragma unroll
      for (int i = 0; i < 4; ++i)
        rs[i] += __shfl_xor(rs[i], off, 64);
    #pragma unroll
    for (int i = 0; i < 4; ++i) lrun[i] = lrun[i] * al[i] + rs[i];
    #pragma unroll
    for (int n = 0; n < 4; ++n)
      #pragma unroll
      for (int i = 0; i < 4; ++i) oacc[n][i] *= al[i];

    // ---- V loads (issued before the P LDS round-trip) ----
    f16x8 vb[8];
    #pragma unroll
    for (int kc = 0; kc < 2; ++kc)
      #pragma unroll
      for (int n = 0; n < 4; ++n)
        vb[kc * 4 + n] = *(const f16x8*)(Vp + (size_t)(n * 16 + c) * SEQ + ts * 64 + kc * 32 + g * 8);

    // ---- mask + stage P (D-frag -> [row][col] LDS) ----
    #pragma unroll
    for (int i = 0; i < 4; ++i)
      #pragma unroll
      for (int n = 0; n < 4; ++n) {
        float p = ((mw[i] >> (n * 16 + c)) & 1ULL) ? sa[n][i] : 0.f;
        myP[(g * 4 + i) * 72 + n * 16 + c] = (f16)p;
      }

    // ---- O += P V (pa from wave-private LDS; compiler inserts lgkmcnt) ----
    #pragma unroll
    for (int kc = 0; kc < 2; ++kc) {
      f16x8 pa = *(const f16x8*)(myP + c * 72 + kc * 32 + g * 8);
      #pragma unroll
      for (int n = 0; n < 4; ++n)
        oacc[n] = MFMA16(pa, vb[kc * 4 + n], oacc[n]);
    }
  }

  // ---- normalize (1/l * 1/cdrop) and store [B,T,E] f16 ----
  #pragma unroll
  for (int i = 0; i < 4; ++i) {
    float isc = inv_cdrop / lrun[i];
    int trow = q0 + g * 4 + i;
    f16* orow = Oa + ((size_t)b * SEQ + trow) * EMB + h * HD;
    #pragma unroll
    for (int n = 0; n < 4; ++n)
      orow[n * 16 + c] = (f16)(oacc[n][i] * isc);
  }
}

// ---------------------------------------------------------------------------
extern "C" void kernel_launch(void* const* d_in, const int* in_sizes, int n_in,
                              void* d_out, int out_size, void* d_ws, size_t ws_size,
                              hipStream_t stream) {
  const float* x     = (const float*)d_in[0];
  const float* noise = (const float*)d_in[1];
  const float* Wq    = (const float*)d_in[2];
  const float* bq    = (const float*)d_in[3];
  const float* Wk    = (const float*)d_in[4];
  const float* bk    = (const float*)d_in[5];
  const float* Wv    = (const float*)d_in[6];
  const float* bv    = (const float*)d_in[7];
  const float* Wo    = (const float*)d_in[8];
  const float* bo    = (const float*)d_in[9];
  const float* theta = (const float*)d_in[10];
  // d_in[11] = corr_w: softmax-invariant per-head constant -> unused

  char* ws = (char*)d_ws;
  float* sc  = (float*)(ws + WS_SC);
  f16* xh    = (f16*)(ws + WS_XH);
  f16* wh    = (f16*)(ws + WS_WQH);          // [Wq|Wk|Wv|Wo] f16
  f16* Qh    = (f16*)(ws + WS_QH);
  f16* Kh    = (f16*)(ws + WS_KH);
  f16* Vth   = (f16*)(ws + WS_VTH);
  f16* Oah   = (f16*)(ws + WS_OA);
  u64* maskw = (u64*)(ws + WS_XH);           // reuses xh after QKV GEMMs

  k_setup<<<1, 64, 0, stream>>>(theta, sc);

  k_cvt8<<<2048, 256, 0, stream>>>(x, xh, MT * EMB / 8);
  k_cvtW<<<2048, 256, 0, stream>>>(Wq, Wk, Wv, Wo, wh);

  dim3 gemm_grid(EMB / 64, MT / 128);   // (16, 32) = 512 blocks
  k_gemm<0><<<gemm_grid, 256, 0, stream>>>(xh, wh,            bq, 0.125f, (void*)Qh);
  k_gemm<0><<<gemm_grid, 256, 0, stream>>>(xh, wh + (1 << 20), bk, 1.0f,  (void*)Kh);
  k_gemm<1><<<gemm_grid, 256, 0, stream>>>(xh, wh + (2 << 20), bv, 1.0f,  (void*)Vth);

  // xh is dead now -> pack noise mask into its space
  k_mask<<<2048, 256, 0, stream>>>(noise, sc, maskw);

  k_attn<<<dim3(SEQ / 64, NB * NH), 256, 0, stream>>>(Qh, Kh, Vth, maskw, sc, Oah);

  k_gemm<2><<<gemm_grid, 256, 0, stream>>>(Oah, wh + (3 << 20), bo, 1.0f, d_out);
}